// Round 8
// baseline (646.585 us; speedup 1.0000x reference)
//
#include <hip/hip_runtime.h>

// LSTM: B=2048, T=512, D=1, H=50, OUT=3, fp32.
// One wave64 per block, one batch element per wave (2048 waves = 2/SIMD).
// Lane j owns hidden unit j; 200 recurrent weights resident per lane.
//
// R1-R7 forensics: ~615 issued VALU-equiv/wave-step vs ~280 useful, scaling
// with resident weight count; FETCH/WRITE flat; VGPR_Count pinned ~108-112.
// Only consistent mechanism: weights homed in AGPRs (unified file), one
// v_accvgpr_read per weight-use. R7's attribute was silently unsupported.
// THIS round: ban AGPRs with a full AGPR clobber inside the hot loop --
// live ranges crossing the asm interfere with a0-a255 and cannot be
// assigned AGPR storage. waves_per_eu(1,2): 512-reg budget, arch cap 256,
// working set ~240 -> weights must get arch VGPRs (or spill to scratch,
// which the counters would expose unambiguously).

#define BB   2048
#define TT   512
#define HH   50

// Clobber every AGPR: any value live across this point cannot live in an AGPR.
#define AGPR_CLOBBER() asm volatile("" ::: \
  "a0","a1","a2","a3","a4","a5","a6","a7","a8","a9","a10","a11","a12","a13","a14","a15", \
  "a16","a17","a18","a19","a20","a21","a22","a23","a24","a25","a26","a27","a28","a29","a30","a31", \
  "a32","a33","a34","a35","a36","a37","a38","a39","a40","a41","a42","a43","a44","a45","a46","a47", \
  "a48","a49","a50","a51","a52","a53","a54","a55","a56","a57","a58","a59","a60","a61","a62","a63", \
  "a64","a65","a66","a67","a68","a69","a70","a71","a72","a73","a74","a75","a76","a77","a78","a79", \
  "a80","a81","a82","a83","a84","a85","a86","a87","a88","a89","a90","a91","a92","a93","a94","a95", \
  "a96","a97","a98","a99","a100","a101","a102","a103","a104","a105","a106","a107","a108","a109","a110","a111", \
  "a112","a113","a114","a115","a116","a117","a118","a119","a120","a121","a122","a123","a124","a125","a126","a127", \
  "a128","a129","a130","a131","a132","a133","a134","a135","a136","a137","a138","a139","a140","a141","a142","a143", \
  "a144","a145","a146","a147","a148","a149","a150","a151","a152","a153","a154","a155","a156","a157","a158","a159", \
  "a160","a161","a162","a163","a164","a165","a166","a167","a168","a169","a170","a171","a172","a173","a174","a175", \
  "a176","a177","a178","a179","a180","a181","a182","a183","a184","a185","a186","a187","a188","a189","a190","a191", \
  "a192","a193","a194","a195","a196","a197","a198","a199","a200","a201","a202","a203","a204","a205","a206","a207", \
  "a208","a209","a210","a211","a212","a213","a214","a215","a216","a217","a218","a219","a220","a221","a222","a223", \
  "a224","a225","a226","a227","a228","a229","a230","a231","a232","a233","a234","a235","a236","a237","a238","a239", \
  "a240","a241","a242","a243","a244","a245","a246","a247","a248","a249","a250","a251","a252","a253","a254","a255")

__device__ __forceinline__ float readlane_f(float v, int lane) {
    union { float f; int i; } u;
    u.f = v;
    u.i = __builtin_amdgcn_readlane(u.i, lane);
    return u.f;
}

__device__ __forceinline__ float fast_sigmoid(float x) {
    float e = __builtin_amdgcn_exp2f(-1.4426950408889634f * x);
    return __builtin_amdgcn_rcpf(1.0f + e);
}

__device__ __forceinline__ float fast_tanh(float x) {
    float e = __builtin_amdgcn_exp2f(-2.8853900817779268f * x);  // e^{-2x}
    return __builtin_amdgcn_rcpf(1.0f + e) * 2.0f - 1.0f;
}

// Apply macro M to k = 0..49
#define REPK(M) \
  M(0)  M(1)  M(2)  M(3)  M(4)  M(5)  M(6)  M(7)  M(8)  M(9)  \
  M(10) M(11) M(12) M(13) M(14) M(15) M(16) M(17) M(18) M(19) \
  M(20) M(21) M(22) M(23) M(24) M(25) M(26) M(27) M(28) M(29) \
  M(30) M(31) M(32) M(33) M(34) M(35) M(36) M(37) M(38) M(39) \
  M(40) M(41) M(42) M(43) M(44) M(45) M(46) M(47) M(48) M(49)

__global__ __launch_bounds__(64)
__attribute__((amdgpu_waves_per_eu(1, 2)))
void lstm_scan_kernel(const float* __restrict__ x,
                      const float* __restrict__ W_ih,
                      const float* __restrict__ W_hh,
                      const float* __restrict__ b_ih,
                      const float* __restrict__ b_hh,
                      const float* __restrict__ fc_w,
                      const float* __restrict__ fc_b,
                      float* __restrict__ out) {
    __shared__ float xs[TT];     // this wave's x row (2 KB)

    const int lane = threadIdx.x;    // block == one wave
    const int b    = blockIdx.x;

    // Stage x row with float4 loads (2 x 1KB coalesced instructions)
    const float4* xg  = (const float4*)(x + b * TT);
    float4*       xs4 = (float4*)xs;
    xs4[lane]      = xg[lane];
    xs4[lane + 64] = xg[lane + 64];
    __syncthreads();

    const int j = (lane < HH) ? lane : (HH - 1);   // clamp idle lanes

    // 200 weight scalars, loaded once.
#define WDECL(k) \
    float w0_##k = W_hh[(0 * HH + j) * HH + (k)]; \
    float w1_##k = W_hh[(1 * HH + j) * HH + (k)]; \
    float w2_##k = W_hh[(2 * HH + j) * HH + (k)]; \
    float w3_##k = W_hh[(3 * HH + j) * HH + (k)];
    REPK(WDECL)
#undef WDECL

    float wi0 = W_ih[0 * HH + j];
    float wi1 = W_ih[1 * HH + j];
    float wi2 = W_ih[2 * HH + j];
    float wi3 = W_ih[3 * HH + j];
    float bs0 = b_ih[0 * HH + j] + b_hh[0 * HH + j];
    float bs1 = b_ih[1 * HH + j] + b_hh[1 * HH + j];
    float bs2 = b_ih[2 * HH + j] + b_hh[2 * HH + j];
    float bs3 = b_ih[3 * HH + j] + b_hh[3 * HH + j];

    float h = 0.0f, c = 0.0f;

    float xc = xs[0];                    // software-pipelined x read
    #pragma unroll 1
    for (int t = 0; t < TT; ++t) {
        AGPR_CLOBBER();                  // weights live across this: no AGPR homes
        const float xn = xs[(t + 1) & (TT - 1)];   // prefetch next step
        float ai = fmaf(xc, wi0, bs0);
        float af = fmaf(xc, wi1, bs1);
        float ag = fmaf(xc, wi2, bs2);
        float ao = fmaf(xc, wi3, bs3);
#define KSTEP(k) { \
        const float hk = readlane_f(h, k); \
        ai = fmaf(hk, w0_##k, ai); \
        af = fmaf(hk, w1_##k, af); \
        ag = fmaf(hk, w2_##k, ag); \
        ao = fmaf(hk, w3_##k, ao); }
        REPK(KSTEP)
#undef KSTEP
        const float ig = fast_sigmoid(ai);
        const float fg = fast_sigmoid(af);
        const float gg = fast_tanh(ag);
        const float og = fast_sigmoid(ao);
        c = fmaf(fg, c, ig * gg);
        h = og * fast_tanh(c);
        xc = xn;
    }

    // Epilogue: out[b][o] = sum_j h_j * fc_w[o][j] + fc_b[o]
    const float hv = (lane < HH) ? h : 0.0f;
    float r0 = hv * fc_w[0 * HH + j];
    float r1 = hv * fc_w[1 * HH + j];
    float r2 = hv * fc_w[2 * HH + j];
    #pragma unroll
    for (int off = 32; off > 0; off >>= 1) {
        r0 += __shfl_down(r0, off, 64);
        r1 += __shfl_down(r1, off, 64);
        r2 += __shfl_down(r2, off, 64);
    }
    if (lane == 0) {
        out[b * 3 + 0] = r0 + fc_b[0];
        out[b * 3 + 1] = r1 + fc_b[1];
        out[b * 3 + 2] = r2 + fc_b[2];
    }
}

extern "C" void kernel_launch(void* const* d_in, const int* in_sizes, int n_in,
                              void* d_out, int out_size, void* d_ws, size_t ws_size,
                              hipStream_t stream) {
    const float* x    = (const float*)d_in[0];
    const float* W_ih = (const float*)d_in[1];
    const float* W_hh = (const float*)d_in[2];
    const float* b_ih = (const float*)d_in[3];
    const float* b_hh = (const float*)d_in[4];
    const float* fc_w = (const float*)d_in[5];
    const float* fc_b = (const float*)d_in[6];
    float* out = (float*)d_out;

    dim3 grid(BB);       // one wave64 block per batch element
    dim3 block(64);
    lstm_scan_kernel<<<grid, block, 0, stream>>>(x, W_ih, W_hh, b_ih, b_hh,
                                                 fc_w, fc_b, out);
}